// Round 7
// baseline (208.698 us; speedup 1.0000x reference)
//
#include <hip/hip_runtime.h>

// Problem constants (from reference)
constexpr int N  = 50000;   // nodes
constexpr int E  = 800000;  // edges
constexpr int C  = 128;     // feature dim (IN_C == HID)
constexpr int G  = 256;     // graphs
constexpr int OC = 64;      // out channels
constexpr int D  = 64;      // ELL padded degree (Poisson(16): P(deg>=64) ~ 1e-20)

constexpr int NBUCK = 196;     // 256-node buckets: bucket = dst >> 8
constexpr int BCAP  = 5120;    // bucket capacity
constexpr int EPB = 2048;                      // edges per binning block
constexpr int EB  = (E + EPB - 1) / EPB;       // 391 edge-binning blocks
constexpr int WB1 = 64;                        // W1a^T -> bf16 blocks
constexpr int WXB = 64;                        // Wx = W1b@W2a -> bf16^T blocks
constexpr int WHB = 32;                        // Whead = W2b@Wl (f32) blocks
constexpr int GB  = (N + 255) / 256;           // 196 batch-histogram blocks
constexpr int FB  = NBUCK;                     // bucket-fill blocks in mid kernel
constexpr int MB  = (N + 63) / 64;             // 782 64-row tiles

typedef __attribute__((ext_vector_type(8))) short short8;
typedef __attribute__((ext_vector_type(4))) float f32x4;
typedef __attribute__((ext_vector_type(2))) float f32x2;

__device__ __forceinline__ unsigned int au(float f) { return __float_as_uint(f); }

__device__ __forceinline__ unsigned short f2bf(float f) {
    unsigned int u = au(f);
    u += 0x7fffu + ((u >> 16) & 1u);   // round-to-nearest-even
    return (unsigned short)(u >> 16);
}
__device__ __forceinline__ unsigned int pack_bf16(float lo, float hi) {
    return ((au(hi) + 0x8000u) & 0xFFFF0000u) | ((au(lo) + 0x8000u) >> 16);
}

// decode 8 fp8(e4m3) in uint2 -> accumulate into 4 float2
__device__ __forceinline__ void acc8(f32x2* a, uint2 v) {
    a[0] += __builtin_amdgcn_cvt_pk_f32_fp8((int)v.x, false);
    a[1] += __builtin_amdgcn_cvt_pk_f32_fp8((int)v.x, true);
    a[2] += __builtin_amdgcn_cvt_pk_f32_fp8((int)v.y, false);
    a[3] += __builtin_amdgcn_cvt_pk_f32_fp8((int)v.y, true);
}
__device__ __forceinline__ void set8(f32x2* a, uint2 v) {
    a[0] = __builtin_amdgcn_cvt_pk_f32_fp8((int)v.x, false);
    a[1] = __builtin_amdgcn_cvt_pk_f32_fp8((int)v.x, true);
    a[2] = __builtin_amdgcn_cvt_pk_f32_fp8((int)v.y, false);
    a[3] = __builtin_amdgcn_cvt_pk_f32_fp8((int)v.y, true);
}

// gather one 64-channel plane of neighbor rows (8 fp8 ch per lane), 8-deep pipeline.
// Plane is 3.2 MB -> L2-resident per XCD while all blocks are in the same pass.
__device__ __forceinline__ void gather_plane(f32x2* a, const uint2* P,
                                             const unsigned short* irow, int dg, int l) {
    const uint4* i8 = (const uint4*)irow;   // 8 u16 indices per load
    int nb  = dg >> 3;
    int rem = dg & 7;
    if (nb > 0) {
        uint4 iu = i8[0];
        int t0 = (int)(iu.x & 0xffffu), t1 = (int)(iu.x >> 16);
        int t2 = (int)(iu.y & 0xffffu), t3 = (int)(iu.y >> 16);
        int t4 = (int)(iu.z & 0xffffu), t5 = (int)(iu.z >> 16);
        int t6 = (int)(iu.w & 0xffffu), t7 = (int)(iu.w >> 16);
        uint2 v0 = P[(size_t)t0 * 8 + l];
        uint2 v1 = P[(size_t)t1 * 8 + l];
        uint2 v2 = P[(size_t)t2 * 8 + l];
        uint2 v3 = P[(size_t)t3 * 8 + l];
        uint2 v4 = P[(size_t)t4 * 8 + l];
        uint2 v5 = P[(size_t)t5 * 8 + l];
        uint2 v6 = P[(size_t)t6 * 8 + l];
        uint2 v7 = P[(size_t)t7 * 8 + l];
        for (int b = 1; b < nb; ++b) {
            uint4 ju = i8[b];
            int u0 = (int)(ju.x & 0xffffu), u1 = (int)(ju.x >> 16);
            int u2 = (int)(ju.y & 0xffffu), u3 = (int)(ju.y >> 16);
            int u4 = (int)(ju.z & 0xffffu), u5 = (int)(ju.z >> 16);
            int u6 = (int)(ju.w & 0xffffu), u7 = (int)(ju.w >> 16);
            uint2 w0 = P[(size_t)u0 * 8 + l];
            uint2 w1 = P[(size_t)u1 * 8 + l];
            uint2 w2 = P[(size_t)u2 * 8 + l];
            uint2 w3 = P[(size_t)u3 * 8 + l];
            uint2 w4 = P[(size_t)u4 * 8 + l];
            uint2 w5 = P[(size_t)u5 * 8 + l];
            uint2 w6 = P[(size_t)u6 * 8 + l];
            uint2 w7 = P[(size_t)u7 * 8 + l];
            // decode previous batch while w* are in flight
            acc8(a, v0); acc8(a, v1); acc8(a, v2); acc8(a, v3);
            acc8(a, v4); acc8(a, v5); acc8(a, v6); acc8(a, v7);
            v0 = w0; v1 = w1; v2 = w2; v3 = w3;
            v4 = w4; v5 = w5; v6 = w6; v7 = w7;
        }
        acc8(a, v0); acc8(a, v1); acc8(a, v2); acc8(a, v3);
        acc8(a, v4); acc8(a, v5); acc8(a, v6); acc8(a, v7);
    }
    if (rem) {
        const unsigned short* ir = irow + nb * 8;
#pragma unroll
        for (int m = 0; m < 7; ++m) {
            if (m < rem) {
                uint2 v = P[(size_t)ir[m] * 8 + l];
                acc8(a, v);
            }
        }
    }
}

// degree-rank sort of the 64 tile nodes (wave 0 only): sorted[rank] = local row.
__device__ __forceinline__ void tile_sort(short* sorted, const int* deg, int row0,
                                          int lane, int wave) {
    if (wave == 0) {
        int n0 = row0 + lane;
        int key = (n0 < N) ? min(deg[n0], D) : -1;
        int rank = 0;
        for (int j = 0; j < 64; ++j) {
            int kj = __shfl(key, j);
            rank += (kj < key) || (kj == key && j < lane);
        }
        sorted[rank] = (short)lane;
    }
}

// ---------------- prep: edge binning || weight fusions || gcnt hist ----------------

__global__ __launch_bounds__(256) void build_prep_kernel(const int* __restrict__ src,
                                                         const int* __restrict__ dst,
                                                         int* __restrict__ bcount,
                                                         unsigned int* __restrict__ bucketbuf,
                                                         const float* __restrict__ W1a,
                                                         const float* __restrict__ W1b,
                                                         const float* __restrict__ W2a,
                                                         const float* __restrict__ W2b,
                                                         const float* __restrict__ Wl,
                                                         const float* __restrict__ bl,
                                                         const float* __restrict__ b1b,
                                                         const float* __restrict__ b2b,
                                                         unsigned short* __restrict__ wt1a,
                                                         unsigned short* __restrict__ wtx,
                                                         float* __restrict__ Whead,
                                                         float* __restrict__ c1,
                                                         float* __restrict__ bhead,
                                                         const int* __restrict__ batch,
                                                         int* __restrict__ gcnt) {
    int b = blockIdx.x;
    int tid = threadIdx.x;
    if (b < EB) {
        __shared__ int lcount[NBUCK];
        __shared__ int lbase[NBUCK];
        __shared__ int lcur[NBUCK];
        for (int i = tid; i < NBUCK; i += 256) { lcount[i] = 0; lcur[i] = 0; }
        __syncthreads();
        int e0 = b * EPB;
        int sv[8], dv[8];
#pragma unroll
        for (int i = 0; i < 8; ++i) {
            int e = e0 + i * 256 + tid;
            if (e < E) {
                sv[i] = src[e];
                dv[i] = dst[e];
                atomicAdd(&lcount[dv[i] >> 8], 1);
            } else {
                dv[i] = -1;
            }
        }
        __syncthreads();
        if (tid < NBUCK) {
            int c = lcount[tid];
            lbase[tid] = (c > 0) ? atomicAdd(&bcount[tid], c) : 0;
        }
        __syncthreads();
#pragma unroll
        for (int i = 0; i < 8; ++i) {
            if (dv[i] >= 0) {
                int bk = dv[i] >> 8;
                int pos = lbase[bk] + atomicAdd(&lcur[bk], 1);
                if (pos < BCAP)
                    bucketbuf[(size_t)bk * BCAP + pos] =
                        ((unsigned int)sv[i] << 16) | (unsigned int)(dv[i] & 255);
            }
        }
    } else if (b < EB + WB1) {
        // W1a^T -> bf16 [n][k]
        int idx = (b - EB) * 256 + tid;     // < 16384
        int n = idx >> 7, k = idx & 127;
        wt1a[idx] = f2bf(W1a[k * 128 + n]);
    } else if (b < EB + WB1 + WXB) {
        // Wx[i][j] = sum_k W1b[i][k]*W2a[k][j]; store transposed bf16 wtx[j][i]
        int idx = (b - EB - WB1) * 256 + tid;  // < 16384
        int i = idx >> 7, j = idx & 127;
        float acc = 0.f;
        for (int k = 0; k < 128; ++k) acc += W1b[i * 128 + k] * W2a[k * 128 + j];
        wtx[j * 128 + i] = f2bf(acc);
    } else if (b < EB + WB1 + WXB + WHB) {
        // Whead[i][j] = sum_k W2b[i][k]*Wl[k][j]  (f32, row-major [128][64])
        int idx = (b - EB - WB1 - WXB) * 256 + tid;  // < 8192
        int i = idx >> 6, j = idx & 63;
        float acc = 0.f;
        for (int k = 0; k < 128; ++k) acc += W2b[i * 128 + k] * Wl[k * OC + j];
        Whead[i * OC + j] = acc;
    } else if (b == EB + WB1 + WXB + WHB) {
        // bias fusions
        if (tid < 128) {
            float acc = 0.f;
            for (int k = 0; k < 128; ++k) acc += b1b[k] * W2a[k * 128 + tid];
            c1[tid] = acc;
        } else if (tid < 192) {
            int j = tid - 128;
            float acc = bl[j];
            for (int k = 0; k < 128; ++k) acc += b2b[k] * Wl[k * OC + j];
            bhead[j] = acc;
        }
    } else {
        // graph-size histogram (batch sorted)
        __shared__ int h[G];
        h[tid] = 0;
        __syncthreads();
        int i = (b - (EB + WB1 + WXB + WHB + 1)) * 256 + tid;
        if (i < N) atomicAdd(&h[batch[i]], 1);
        __syncthreads();
        int c = h[tid];
        if (c > 0) atomicAdd(&gcnt[tid], c);
    }
}

// ---------------- mid: bucket-fill (196 blocks) || GEMM Z1 = X@W1a (782 blocks) --------
// Z1 written PLANE-SPLIT: z[p][node][64ch] fp8, plane = 3.2 MB (fits one XCD L2).

__global__ __launch_bounds__(512, 6) void mid_kernel(const int* __restrict__ bcount,
                                                     const unsigned int* __restrict__ bucketbuf,
                                                     unsigned short* __restrict__ ell,
                                                     int* __restrict__ deg,
                                                     const float* __restrict__ x,
                                                     const unsigned short* __restrict__ wt1a,
                                                     unsigned char* __restrict__ z1) {
    int tid = threadIdx.x;
    if (blockIdx.x < FB) {
        __shared__ int lcur[256];
        int b = blockIdx.x;
        if (tid < 256) lcur[tid] = 0;
        __syncthreads();
        int cnt = min(bcount[b], BCAP);
        const unsigned int* buf = bucketbuf + (size_t)b * BCAP;
        int nbase = b << 8;
        for (int i = tid; i < cnt; i += 512) {
            unsigned int e = buf[i];
            int dlow = (int)(e & 255u);
            int p = atomicAdd(&lcur[dlow], 1);
            if (p < D) ell[(size_t)(nbase + dlow) * D + p] = (unsigned short)(e >> 16);
        }
        __syncthreads();
        if (tid < 256) {
            int node = nbase + tid;
            if (node < N) deg[node] = lcur[tid];
        }
        return;
    }
    // ---- gemma: Z1 = X @ W1a (f32 in, fp8 out plane-split), 8-wave partition ----
    constexpr int LD = 136;
    __shared__ short Xl[64 * LD];
    __shared__ short Wl[128 * LD];
    int lane = tid & 63, wave = tid >> 6;
    int row0 = (blockIdx.x - FB) * 64;

    const short8* Wg = (const short8*)wt1a;
#pragma unroll
    for (int i = tid; i < 2048; i += 512) {
        int r = i >> 4, c = i & 15;
        *((short8*)(Wl + r * LD) + c) = Wg[i];
    }
    const float4* x4 = (const float4*)(x + (size_t)row0 * C);
#pragma unroll
    for (int i = tid; i < 2048; i += 512) {
        int r = i >> 5, c4 = i & 31;
        float4 v = (row0 + r < N) ? x4[i] : make_float4(0.f, 0.f, 0.f, 0.f);
        uint2 u;
        u.x = pack_bf16(v.x, v.y);
        u.y = pack_bf16(v.z, v.w);
        *(uint2*)(Xl + r * LD + c4 * 4) = u;
    }

    int mw = wave >> 2, nw = wave & 3;
    int lid = lane & 15, quad = lane >> 4;
    f32x4 acc[2][2];
#pragma unroll
    for (int nt = 0; nt < 2; ++nt) {
        acc[0][nt] = (f32x4){0.f, 0.f, 0.f, 0.f};
        acc[1][nt] = (f32x4){0.f, 0.f, 0.f, 0.f};
    }
    __syncthreads();

#pragma unroll
    for (int ks = 0; ks < 4; ++ks) {
        short8 a0 = *(const short8*)(Xl + (mw * 32 + lid) * LD + ks * 32 + quad * 8);
        short8 a1 = *(const short8*)(Xl + (mw * 32 + 16 + lid) * LD + ks * 32 + quad * 8);
#pragma unroll
        for (int nt = 0; nt < 2; ++nt) {
            short8 bf = *(const short8*)(Wl + (nw * 32 + nt * 16 + lid) * LD + ks * 32 + quad * 8);
            acc[0][nt] = __builtin_amdgcn_mfma_f32_16x16x32_bf16(a0, bf, acc[0][nt], 0, 0, 0);
            acc[1][nt] = __builtin_amdgcn_mfma_f32_16x16x32_bf16(a1, bf, acc[1][nt], 0, 0, 0);
        }
    }

#pragma unroll
    for (int mt = 0; mt < 2; ++mt) {
#pragma unroll
        for (int nt = 0; nt < 2; ++nt) {
            int mbase = row0 + mw * 32 + mt * 16 + quad * 4;
            int n = nw * 32 + nt * 16 + lid;
            size_t pbase = (size_t)(n >> 6) * N * 64 + (n & 63);
            f32x4 v = acc[mt][nt];
#pragma unroll
            for (int r = 0; r < 4; ++r) {
                int row = mbase + r;
                if (row < N) {
                    unsigned int p = (unsigned int)__builtin_amdgcn_cvt_pk_fp8_f32(v[r], 0.f, 0, false);
                    z1[pbase + (size_t)row * 64] = (unsigned char)(p & 0xFF);
                }
            }
        }
    }
}

// ---------------- k2: plane-split gather(Z1) + b1a -> relu -> GEMM(Wx) -> Z2 -----------

__global__ __launch_bounds__(512, 6) void k2_kernel(const unsigned char* __restrict__ z1,
                                                    const int* __restrict__ deg,
                                                    const unsigned short* __restrict__ ell,
                                                    const unsigned short* __restrict__ wtx,
                                                    const float* __restrict__ b1a,
                                                    unsigned char* __restrict__ z2) {
    constexpr int LD = 136;
    __shared__ short Xl[64 * LD];
    __shared__ short Wl[128 * LD];
    __shared__ short sorted[64];
    int tid = threadIdx.x;
    int lane = tid & 63, wave = tid >> 6;
    int row0 = blockIdx.x * 64;

    const short8* Wg = (const short8*)wtx;
#pragma unroll
    for (int i = tid; i < 2048; i += 512) {
        int r = i >> 4, c = i & 15;
        *((short8*)(Wl + r * LD) + c) = Wg[i];
    }
    tile_sort(sorted, deg, row0, lane, wave);
    __syncthreads();

    {
        int grp = tid >> 3;   // 0..63: rank in degree order
        int l   = tid & 7;    // 8 channels per plane each
        int lr  = sorted[grp];
        int n = row0 + lr;
        int dgc = (n < N) ? min(deg[n], D) : 0;
        const unsigned short* irow = ell + (size_t)n * D;
#pragma unroll 1
        for (int p = 0; p < 2; ++p) {
            const uint2* P = (const uint2*)(z1 + (size_t)p * N * 64);
            f32x2 a[4];
            if (n < N) {
                set8(a, P[(size_t)n * 8 + l]);       // self
                gather_plane(a, P, irow, dgc, l);
                const f32x2* bp = (const f32x2*)(b1a + p * 64 + l * 8);
#pragma unroll
                for (int q = 0; q < 4; ++q) {
                    a[q] += bp[q];
                    a[q].x = fmaxf(a[q].x, 0.f);
                    a[q].y = fmaxf(a[q].y, 0.f);
                }
            } else {
#pragma unroll
                for (int q = 0; q < 4; ++q) a[q] = (f32x2){0.f, 0.f};
            }
            uint4 o;
            o.x = pack_bf16(a[0].x, a[0].y); o.y = pack_bf16(a[1].x, a[1].y);
            o.z = pack_bf16(a[2].x, a[2].y); o.w = pack_bf16(a[3].x, a[3].y);
            *(uint4*)(Xl + lr * LD + p * 64 + l * 8) = o;
        }
    }

    int mw = wave >> 2, nw = wave & 3;
    int lid = lane & 15, quad = lane >> 4;
    f32x4 acc[2][2];
#pragma unroll
    for (int nt = 0; nt < 2; ++nt) {
        acc[0][nt] = (f32x4){0.f, 0.f, 0.f, 0.f};
        acc[1][nt] = (f32x4){0.f, 0.f, 0.f, 0.f};
    }
    __syncthreads();

#pragma unroll
    for (int ks = 0; ks < 4; ++ks) {
        short8 a0 = *(const short8*)(Xl + (mw * 32 + lid) * LD + ks * 32 + quad * 8);
        short8 a1 = *(const short8*)(Xl + (mw * 32 + 16 + lid) * LD + ks * 32 + quad * 8);
#pragma unroll
        for (int nt = 0; nt < 2; ++nt) {
            short8 bf = *(const short8*)(Wl + (nw * 32 + nt * 16 + lid) * LD + ks * 32 + quad * 8);
            acc[0][nt] = __builtin_amdgcn_mfma_f32_16x16x32_bf16(a0, bf, acc[0][nt], 0, 0, 0);
            acc[1][nt] = __builtin_amdgcn_mfma_f32_16x16x32_bf16(a1, bf, acc[1][nt], 0, 0, 0);
        }
    }

#pragma unroll
    for (int mt = 0; mt < 2; ++mt) {
#pragma unroll
        for (int nt = 0; nt < 2; ++nt) {
            int mbase = row0 + mw * 32 + mt * 16 + quad * 4;
            int n = nw * 32 + nt * 16 + lid;
            size_t pbase = (size_t)(n >> 6) * N * 64 + (n & 63);
            f32x4 v = acc[mt][nt];
#pragma unroll
            for (int r = 0; r < 4; ++r) {
                int row = mbase + r;
                if (row < N) {
                    unsigned int p = (unsigned int)__builtin_amdgcn_cvt_pk_fp8_f32(v[r], 0.f, 0, false);
                    z2[pbase + (size_t)row * 64] = (unsigned char)(p & 0xFF);
                }
            }
        }
    }
}

// ---------------- k3: plane-split gather(Z2) + (1+deg)*c1 + b2a -> relu -> pool --------

__global__ __launch_bounds__(512, 6) void k3_kernel(const unsigned char* __restrict__ z2,
                                                    const int* __restrict__ deg,
                                                    const unsigned short* __restrict__ ell,
                                                    const float* __restrict__ c1,
                                                    const float* __restrict__ b2a,
                                                    const int* __restrict__ batch,
                                                    float* __restrict__ gsum) {
    constexpr int LD = 136;
    __shared__ short Xl[64 * LD];
    __shared__ short sorted[64];
    int tid = threadIdx.x;
    int lane = tid & 63, wave = tid >> 6;
    int row0 = blockIdx.x * 64;

    tile_sort(sorted, deg, row0, lane, wave);
    __syncthreads();

    {
        int grp = tid >> 3;
        int l   = tid & 7;
        int lr  = sorted[grp];
        int n = row0 + lr;
        int dfull = (n < N) ? deg[n] : 0;
        int dgc = min(dfull, D);
        float degf = (float)(1 + dfull);
        const unsigned short* irow = ell + (size_t)n * D;
#pragma unroll 1
        for (int p = 0; p < 2; ++p) {
            const uint2* P = (const uint2*)(z2 + (size_t)p * N * 64);
            f32x2 a[4];
            if (n < N) {
                set8(a, P[(size_t)n * 8 + l]);       // self
                gather_plane(a, P, irow, dgc, l);
                const f32x2* c1p = (const f32x2*)(c1 + p * 64 + l * 8);
                const f32x2* b2p = (const f32x2*)(b2a + p * 64 + l * 8);
#pragma unroll
                for (int q = 0; q < 4; ++q) {
                    a[q] += degf * c1p[q] + b2p[q];
                    a[q].x = fmaxf(a[q].x, 0.f);
                    a[q].y = fmaxf(a[q].y, 0.f);
                }
            } else {
#pragma unroll
                for (int q = 0; q < 4; ++q) a[q] = (f32x2){0.f, 0.f};
            }
            uint4 o;
            o.x = pack_bf16(a[0].x, a[0].y); o.y = pack_bf16(a[1].x, a[1].y);
            o.z = pack_bf16(a[2].x, a[2].y); o.w = pack_bf16(a[3].x, a[3].y);
            *(uint4*)(Xl + lr * LD + p * 64 + l * 8) = o;
        }
    }
    __syncthreads();

    // pool: wave w owns rows [w*8, w*8+8) in NATURAL order; lane owns ch {2l, 2l+1}.
    int r0 = wave * 8;
    int gprev = -1;
    float a0 = 0.f, a1 = 0.f;
    for (int rr = 0; rr < 8; ++rr) {
        int row = row0 + r0 + rr;
        if (row >= N) break;
        int g = batch[row];
        if (g != gprev) {
            if (gprev >= 0) {
                atomicAdd(&gsum[gprev * C + 2 * lane], a0);
                atomicAdd(&gsum[gprev * C + 2 * lane + 1], a1);
            }
            gprev = g; a0 = 0.f; a1 = 0.f;
        }
        unsigned int pv = *(const unsigned int*)(Xl + (r0 + rr) * LD + 2 * lane);
        a0 += __uint_as_float((pv & 0xffffu) << 16);
        a1 += __uint_as_float(pv & 0xffff0000u);
    }
    if (gprev >= 0) {
        atomicAdd(&gsum[gprev * C + 2 * lane], a0);
        atomicAdd(&gsum[gprev * C + 2 * lane + 1], a1);
    }
}

// ---------------- head: out[g] = (gsum[g]/cnt) @ Whead + bhead  (all f32) --------------

__global__ __launch_bounds__(64) void head_kernel(const float* __restrict__ gsum,
                                                  const int* __restrict__ gcnt,
                                                  const float* __restrict__ Whead,
                                                  const float* __restrict__ bhead,
                                                  float* __restrict__ out) {
    int g = blockIdx.x;
    int t = threadIdx.x;   // 0..63
    __shared__ float pooled[C];
    float inv = 1.0f / (float)max(gcnt[g], 1);
    pooled[t]      = gsum[g * C + t] * inv;
    pooled[t + 64] = gsum[g * C + 64 + t] * inv;
    __syncthreads();
    float o = bhead[t];
#pragma unroll 4
    for (int k = 0; k < C; ++k) o += pooled[k] * Whead[k * OC + t];
    out[g * OC + t] = o;
}

// ---------------- launch ----------------

extern "C" void kernel_launch(void* const* d_in, const int* in_sizes, int n_in,
                              void* d_out, int out_size, void* d_ws, size_t ws_size,
                              hipStream_t stream) {
    const float* x    = (const float*)d_in[0];
    const int*   ei   = (const int*)d_in[1];   // [2,E]
    const int*   bat  = (const int*)d_in[2];
    const float* W1a  = (const float*)d_in[3];
    const float* b1a  = (const float*)d_in[4];
    const float* W1b  = (const float*)d_in[5];
    const float* b1b  = (const float*)d_in[6];
    const float* W2a  = (const float*)d_in[7];
    const float* b2a  = (const float*)d_in[8];
    const float* W2b  = (const float*)d_in[9];
    const float* b2b  = (const float*)d_in[10];
    const float* Wl   = (const float*)d_in[11];
    const float* bl   = (const float*)d_in[12];
    float*       out  = (float*)d_out;

    // workspace: [gsum G*C][gcnt G][bcount NBUCK]  <- one memset
    float* gsum    = (float*)d_ws;                         // G*C f32
    int*   gcnt    = (int*)(gsum + G * C);                 // G
    int*   bcount  = gcnt + G;                             // NBUCK
    int*   deg     = bcount + NBUCK;                       // N (written by mid fill)
    unsigned int*   bucketbuf = (unsigned int*)(deg + N);  // NBUCK*BCAP u32 (4 MB)
    unsigned short* ell  = (unsigned short*)(bucketbuf + (size_t)NBUCK * BCAP);  // N*D
    unsigned short* wt1a = ell + (size_t)N * D;            // 16384 bf16
    unsigned short* wtx  = wt1a + 16384;                   // 16384 bf16
    float* Whead = (float*)(wtx + 16384);                  // 128*64 f32
    float* c1    = Whead + 128 * OC;                       // 128 f32
    float* bhead = c1 + 128;                               // 64 f32
    unsigned char* z1 = (unsigned char*)(bhead + OC);      // 2 planes x N*64 fp8
    unsigned char* z2 = z1 + (size_t)2 * N * 64;           // 2 planes x N*64 fp8

    const int* src = ei;
    const int* dst = ei + E;

    hipMemsetAsync(gsum, 0, (size_t)(G * C + G + NBUCK) * sizeof(int), stream);

    // prep: edge binning + weight fusions + gcnt histogram
    build_prep_kernel<<<EB + WB1 + WXB + WHB + 1 + GB, 256, 0, stream>>>(
        src, dst, bcount, bucketbuf, W1a, W1b, W2a, W2b, Wl, bl, b1b, b2b,
        wt1a, wtx, Whead, c1, bhead, bat, gcnt);

    // mid: bucket fill (196 blocks) || Z1 = X @ W1a (782 blocks, plane-split out)
    mid_kernel<<<FB + MB, 512, 0, stream>>>(bcount, bucketbuf, ell, deg,
                                            x, wt1a, z1);

    // T1 = relu(Z1_i + sum Z1_j + b1a); Z2 = T1 @ (W1b@W2a) (plane-split fp8)
    k2_kernel<<<MB, 512, 0, stream>>>(z1, deg, ell, wtx, b1a, z2);
    // T2 = relu(Z2_i + sum Z2_j + (1+deg)*c1 + b2a); pool sums per graph
    k3_kernel<<<MB, 512, 0, stream>>>(z2, deg, ell, c1, b2a, bat, gsum);
    // out = (pooled mean) @ (W2b@Wl) + (b2b@Wl + bl)
    head_kernel<<<G, 64, 0, stream>>>(gsum, gcnt, Whead, bhead, out);
}

// Round 8
// 194.209 us; speedup vs baseline: 1.0746x; 1.0746x over previous
//
#include <hip/hip_runtime.h>

// Problem constants (from reference)
constexpr int N  = 50000;   // nodes
constexpr int E  = 800000;  // edges
constexpr int C  = 128;     // feature dim (IN_C == HID)
constexpr int G  = 256;     // graphs
constexpr int OC = 64;      // out channels
constexpr int D  = 64;      // ELL padded degree (Poisson(16): P(deg>=64) ~ 1e-20)

constexpr int NBUCK = 196;     // 256-node buckets: bucket = dst >> 8
constexpr int BCAP  = 5120;    // bucket capacity
constexpr int EPB = 2048;                      // edges per binning block
constexpr int EB  = (E + EPB - 1) / EPB;       // 391 edge-binning blocks
constexpr int MB  = (N + 63) / 64;             // 782 64-row tiles (gemma + k2/k3 grids)
constexpr int WXB = 32;                        // Wx = W1b@W2a -> bf16^T blocks (512 thr)
constexpr int WHB = 16;                        // Whead = W2b@Wl (f32) blocks (512 thr)
constexpr int GB  = (N + 511) / 512;           // 98 batch-histogram blocks (512 thr)

typedef __attribute__((ext_vector_type(8))) short short8;
typedef __attribute__((ext_vector_type(4))) float f32x4;
typedef __attribute__((ext_vector_type(2))) float f32x2;

__device__ __forceinline__ unsigned int au(float f) { return __float_as_uint(f); }

__device__ __forceinline__ unsigned short f2bf(float f) {
    unsigned int u = au(f);
    u += 0x7fffu + ((u >> 16) & 1u);   // round-to-nearest-even
    return (unsigned short)(u >> 16);
}
__device__ __forceinline__ unsigned int pack_bf16(float lo, float hi) {
    return ((au(hi) + 0x8000u) & 0xFFFF0000u) | ((au(lo) + 0x8000u) >> 16);
}

// decode 16 fp8(e4m3) in uint4 -> accumulate into 8 float2
__device__ __forceinline__ void acc16(f32x2* a, uint4 v) {
    a[0] += __builtin_amdgcn_cvt_pk_f32_fp8((int)v.x, false);
    a[1] += __builtin_amdgcn_cvt_pk_f32_fp8((int)v.x, true);
    a[2] += __builtin_amdgcn_cvt_pk_f32_fp8((int)v.y, false);
    a[3] += __builtin_amdgcn_cvt_pk_f32_fp8((int)v.y, true);
    a[4] += __builtin_amdgcn_cvt_pk_f32_fp8((int)v.z, false);
    a[5] += __builtin_amdgcn_cvt_pk_f32_fp8((int)v.z, true);
    a[6] += __builtin_amdgcn_cvt_pk_f32_fp8((int)v.w, false);
    a[7] += __builtin_amdgcn_cvt_pk_f32_fp8((int)v.w, true);
}
__device__ __forceinline__ void set16(f32x2* a, uint4 v) {
    a[0] = __builtin_amdgcn_cvt_pk_f32_fp8((int)v.x, false);
    a[1] = __builtin_amdgcn_cvt_pk_f32_fp8((int)v.x, true);
    a[2] = __builtin_amdgcn_cvt_pk_f32_fp8((int)v.y, false);
    a[3] = __builtin_amdgcn_cvt_pk_f32_fp8((int)v.y, true);
    a[4] = __builtin_amdgcn_cvt_pk_f32_fp8((int)v.z, false);
    a[5] = __builtin_amdgcn_cvt_pk_f32_fp8((int)v.z, true);
    a[6] = __builtin_amdgcn_cvt_pk_f32_fp8((int)v.w, false);
    a[7] = __builtin_amdgcn_cvt_pk_f32_fp8((int)v.w, true);
}

// gather neighbor rows (fp8, 16 ch per lane), 4-deep pipeline, NEXT-index prefetch:
// the index pair for batch b+1 is loaded before decoding batch b-1, so its latency
// hides under the decode instead of serializing ahead of the data loads.
__device__ __forceinline__ void gather_rows(f32x2* a, const uint4* F16,
                                            const unsigned short* irow, int dg, int l) {
    const uint2* i2 = (const uint2*)irow;   // 4 u16 indices per load
    int nb  = dg >> 2;
    int rem = dg & 3;
    if (nb > 0) {
        uint2 iu = i2[0];
        int t0 = (int)(iu.x & 0xffffu), t1 = (int)(iu.x >> 16);
        int t2 = (int)(iu.y & 0xffffu), t3 = (int)(iu.y >> 16);
        uint4 v0 = F16[(size_t)t0 * 8 + l];
        uint4 v1 = F16[(size_t)t1 * 8 + l];
        uint4 v2 = F16[(size_t)t2 * 8 + l];
        uint4 v3 = F16[(size_t)t3 * 8 + l];
        uint2 jn;
        if (nb > 1) jn = i2[1];
        for (int b = 1; b < nb; ++b) {
            int u0 = (int)(jn.x & 0xffffu), u1 = (int)(jn.x >> 16);
            int u2 = (int)(jn.y & 0xffffu), u3 = (int)(jn.y >> 16);
            uint4 w0 = F16[(size_t)u0 * 8 + l];
            uint4 w1 = F16[(size_t)u1 * 8 + l];
            uint4 w2 = F16[(size_t)u2 * 8 + l];
            uint4 w3 = F16[(size_t)u3 * 8 + l];
            if (b + 1 < nb) jn = i2[b + 1];   // prefetch next index pair
            // decode previous batch while w* (and jn) are in flight
            acc16(a, v0); acc16(a, v1); acc16(a, v2); acc16(a, v3);
            v0 = w0; v1 = w1; v2 = w2; v3 = w3;
        }
        acc16(a, v0); acc16(a, v1); acc16(a, v2); acc16(a, v3);
    }
    if (rem) {
        const unsigned short* ir = irow + nb * 4;
#pragma unroll
        for (int m = 0; m < 3; ++m) {
            if (m < rem) {
                uint4 v = F16[(size_t)ir[m] * 8 + l];
                acc16(a, v);
            }
        }
    }
}

// degree-rank sort of the 64 tile nodes (wave 0 only): sorted[rank] = local row.
__device__ __forceinline__ void tile_sort(short* sorted, const int* deg, int row0,
                                          int lane, int wave) {
    if (wave == 0) {
        int n0 = row0 + lane;
        int key = (n0 < N) ? min(deg[n0], D) : -1;
        int rank = 0;
        for (int j = 0; j < 64; ++j) {
            int kj = __shfl(key, j);
            rank += (kj < key) || (kj == key && j < lane);
        }
        sorted[rank] = (short)lane;
    }
}

// ---------------- prep: edge binning || gemma Z1=X@W1a || weight fusions || gcnt -------
// gemma depends only on inputs, so its 782 GEMM blocks run INSIDE prep, soaking up the
// CUs that the latency-bound binning blocks leave idle. W1a is converted f32->bf16
// inline per block (64 KB, L2-hot across all blocks).

__global__ __launch_bounds__(512, 6) void build_prep_kernel(const int* __restrict__ src,
                                                            const int* __restrict__ dst,
                                                            int* __restrict__ bcount,
                                                            unsigned int* __restrict__ bucketbuf,
                                                            const float* __restrict__ W1a,
                                                            const float* __restrict__ W1b,
                                                            const float* __restrict__ W2a,
                                                            const float* __restrict__ W2b,
                                                            const float* __restrict__ Wlin,
                                                            const float* __restrict__ bl,
                                                            const float* __restrict__ b1b,
                                                            const float* __restrict__ b2b,
                                                            unsigned short* __restrict__ wtx,
                                                            float* __restrict__ Whead,
                                                            float* __restrict__ c1,
                                                            float* __restrict__ bhead,
                                                            const int* __restrict__ batch,
                                                            int* __restrict__ gcnt,
                                                            const float* __restrict__ x,
                                                            unsigned char* __restrict__ z1) {
    constexpr int LD = 136;
    __shared__ __attribute__((aligned(16))) char smem[64 * LD * 2 + 128 * LD * 2];
    int b = blockIdx.x;
    int tid = threadIdx.x;
    if (b < EB) {
        // ---- edge binning ----
        int* lcount = (int*)smem;
        int* lbase  = lcount + NBUCK;
        int* lcur   = lbase + NBUCK;
        if (tid < NBUCK) { lcount[tid] = 0; lcur[tid] = 0; }
        __syncthreads();
        int e0 = b * EPB;
        int sv[4], dv[4];
#pragma unroll
        for (int i = 0; i < 4; ++i) {
            int e = e0 + i * 512 + tid;
            if (e < E) {
                sv[i] = src[e];
                dv[i] = dst[e];
                atomicAdd(&lcount[dv[i] >> 8], 1);
            } else {
                dv[i] = -1;
            }
        }
        __syncthreads();
        if (tid < NBUCK) {
            int c = lcount[tid];
            lbase[tid] = (c > 0) ? atomicAdd(&bcount[tid], c) : 0;
        }
        __syncthreads();
#pragma unroll
        for (int i = 0; i < 4; ++i) {
            if (dv[i] >= 0) {
                int bk = dv[i] >> 8;
                int pos = lbase[bk] + atomicAdd(&lcur[bk], 1);
                if (pos < BCAP)
                    bucketbuf[(size_t)bk * BCAP + pos] =
                        ((unsigned int)sv[i] << 16) | (unsigned int)(dv[i] & 255);
            }
        }
    } else if (b < EB + MB) {
        // ---- gemma: Z1 = X @ W1a (f32 in, fp8 out), inline W conversion ----
        short* Xl = (short*)smem;              // 64*LD
        short* Wl = (short*)smem + 64 * LD;    // 128*LD
        int lane = tid & 63, wave = tid >> 6;
        int row0 = (b - EB) * 64;

        // Wl[n][k] = bf16(W1a[k][n]); coalesced f32 read, scattered LDS b16 write
        for (int i = tid; i < 16384; i += 512) {
            int k = i >> 7, n = i & 127;
            Wl[n * LD + k] = (short)f2bf(W1a[i]);
        }
        const float4* x4 = (const float4*)(x + (size_t)row0 * C);
        for (int i = tid; i < 2048; i += 512) {
            int r = i >> 5, c4 = i & 31;
            float4 v = (row0 + r < N) ? x4[i] : make_float4(0.f, 0.f, 0.f, 0.f);
            uint2 u;
            u.x = pack_bf16(v.x, v.y);
            u.y = pack_bf16(v.z, v.w);
            *(uint2*)(Xl + r * LD + c4 * 4) = u;
        }

        int mw = wave >> 2, nw = wave & 3;
        int lid = lane & 15, quad = lane >> 4;
        f32x4 acc[2][2];
#pragma unroll
        for (int nt = 0; nt < 2; ++nt) {
            acc[0][nt] = (f32x4){0.f, 0.f, 0.f, 0.f};
            acc[1][nt] = (f32x4){0.f, 0.f, 0.f, 0.f};
        }
        __syncthreads();

#pragma unroll
        for (int ks = 0; ks < 4; ++ks) {
            short8 a0 = *(const short8*)(Xl + (mw * 32 + lid) * LD + ks * 32 + quad * 8);
            short8 a1 = *(const short8*)(Xl + (mw * 32 + 16 + lid) * LD + ks * 32 + quad * 8);
#pragma unroll
            for (int nt = 0; nt < 2; ++nt) {
                short8 bf = *(const short8*)(Wl + (nw * 32 + nt * 16 + lid) * LD + ks * 32 + quad * 8);
                acc[0][nt] = __builtin_amdgcn_mfma_f32_16x16x32_bf16(a0, bf, acc[0][nt], 0, 0, 0);
                acc[1][nt] = __builtin_amdgcn_mfma_f32_16x16x32_bf16(a1, bf, acc[1][nt], 0, 0, 0);
            }
        }

#pragma unroll
        for (int mt = 0; mt < 2; ++mt) {
#pragma unroll
            for (int nt = 0; nt < 2; ++nt) {
                int mbase = row0 + mw * 32 + mt * 16 + quad * 4;
                int n = nw * 32 + nt * 16 + lid;
                f32x4 v = acc[mt][nt];
#pragma unroll
                for (int r = 0; r < 4; ++r) {
                    int row = mbase + r;
                    if (row < N) {
                        unsigned int p = (unsigned int)__builtin_amdgcn_cvt_pk_fp8_f32(v[r], 0.f, 0, false);
                        z1[(size_t)row * 128 + n] = (unsigned char)(p & 0xFF);
                    }
                }
            }
        }
    } else if (b < EB + MB + WXB) {
        // Wx[i][j] = sum_k W1b[i][k]*W2a[k][j]; store transposed bf16 wtx[j][i]
        int idx = (b - EB - MB) * 512 + tid;   // < 16384
        int i = idx >> 7, j = idx & 127;
        float acc = 0.f;
        for (int k = 0; k < 128; ++k) acc += W1b[i * 128 + k] * W2a[k * 128 + j];
        wtx[j * 128 + i] = f2bf(acc);
    } else if (b < EB + MB + WXB + WHB) {
        // Whead[i][j] = sum_k W2b[i][k]*Wl[k][j]  (f32, row-major [128][64])
        int idx = (b - EB - MB - WXB) * 512 + tid;   // < 8192
        int i = idx >> 6, j = idx & 63;
        float acc = 0.f;
        for (int k = 0; k < 128; ++k) acc += W2b[i * 128 + k] * Wlin[k * OC + j];
        Whead[i * OC + j] = acc;
    } else if (b == EB + MB + WXB + WHB) {
        // bias fusions
        if (tid < 128) {
            float acc = 0.f;
            for (int k = 0; k < 128; ++k) acc += b1b[k] * W2a[k * 128 + tid];
            c1[tid] = acc;
        } else if (tid < 192) {
            int j = tid - 128;
            float acc = bl[j];
            for (int k = 0; k < 128; ++k) acc += b2b[k] * Wlin[k * OC + j];
            bhead[j] = acc;
        }
    } else {
        // graph-size histogram (batch sorted)
        int* h = (int*)smem;
        if (tid < G) h[tid] = 0;
        __syncthreads();
        int i = (b - (EB + MB + WXB + WHB + 1)) * 512 + tid;
        if (i < N) atomicAdd(&h[batch[i]], 1);
        __syncthreads();
        if (tid < G) {
            int c = h[tid];
            if (c > 0) atomicAdd(&gcnt[tid], c);
        }
    }
}

// ---------------- fill: per-bucket ELL fill, LDS cursors, node-major ELL [n][D] --------

__global__ __launch_bounds__(512) void fill_kernel(const int* __restrict__ bcount,
                                                   const unsigned int* __restrict__ bucketbuf,
                                                   unsigned short* __restrict__ ell,
                                                   int* __restrict__ deg) {
    __shared__ int lcur[256];
    int b = blockIdx.x;
    int tid = threadIdx.x;
    if (tid < 256) lcur[tid] = 0;
    __syncthreads();
    int cnt = min(bcount[b], BCAP);
    const unsigned int* buf = bucketbuf + (size_t)b * BCAP;
    int nbase = b << 8;
    for (int i = tid; i < cnt; i += 512) {
        unsigned int e = buf[i];
        int dlow = (int)(e & 255u);
        int p = atomicAdd(&lcur[dlow], 1);
        if (p < D) ell[(size_t)(nbase + dlow) * D + p] = (unsigned short)(e >> 16);
    }
    __syncthreads();
    if (tid < 256) {
        int node = nbase + tid;
        if (node < N) deg[node] = lcur[tid];
    }
}

// ---------------- k2: gather(Z1) + b1a -> relu -> GEMM(Wx) -> Z2 fp8 table -------------

__global__ __launch_bounds__(512, 6) void k2_kernel(const unsigned char* __restrict__ z1,
                                                    const int* __restrict__ deg,
                                                    const unsigned short* __restrict__ ell,
                                                    const unsigned short* __restrict__ wtx,
                                                    const float* __restrict__ b1a,
                                                    unsigned char* __restrict__ z2) {
    constexpr int LD = 136;
    __shared__ short Xl[64 * LD];
    __shared__ short Wl[128 * LD];
    __shared__ short sorted[64];
    int tid = threadIdx.x;
    int lane = tid & 63, wave = tid >> 6;
    int row0 = blockIdx.x * 64;

    const short8* Wg = (const short8*)wtx;
#pragma unroll
    for (int i = tid; i < 2048; i += 512) {
        int r = i >> 4, c = i & 15;
        *((short8*)(Wl + r * LD) + c) = Wg[i];
    }
    tile_sort(sorted, deg, row0, lane, wave);
    __syncthreads();

    {
        int grp = tid >> 3;   // 0..63: rank in degree order
        int l   = tid & 7;    // 16 channels each
        int lr  = sorted[grp];
        const uint4* F16 = (const uint4*)z1;
        int n = row0 + lr;
        f32x2 a[8];
        if (n < N) {
            int dgc = min(deg[n], D);
            set16(a, F16[(size_t)n * 8 + l]);       // self
            gather_rows(a, F16, ell + (size_t)n * D, dgc, l);
            const f32x2* bp = (const f32x2*)(b1a + l * 16);
#pragma unroll
            for (int q = 0; q < 8; ++q) {
                a[q] += bp[q];
                a[q].x = fmaxf(a[q].x, 0.f);
                a[q].y = fmaxf(a[q].y, 0.f);
            }
        } else {
#pragma unroll
            for (int q = 0; q < 8; ++q) a[q] = (f32x2){0.f, 0.f};
        }
        uint4 o0, o1;
        o0.x = pack_bf16(a[0].x, a[0].y); o0.y = pack_bf16(a[1].x, a[1].y);
        o0.z = pack_bf16(a[2].x, a[2].y); o0.w = pack_bf16(a[3].x, a[3].y);
        o1.x = pack_bf16(a[4].x, a[4].y); o1.y = pack_bf16(a[5].x, a[5].y);
        o1.z = pack_bf16(a[6].x, a[6].y); o1.w = pack_bf16(a[7].x, a[7].y);
        uint4* xp = (uint4*)(Xl + lr * LD + l * 16);
        xp[0] = o0;
        xp[1] = o1;
    }

    int mw = wave >> 2, nw = wave & 3;
    int lid = lane & 15, quad = lane >> 4;
    f32x4 acc[2][2];
#pragma unroll
    for (int nt = 0; nt < 2; ++nt) {
        acc[0][nt] = (f32x4){0.f, 0.f, 0.f, 0.f};
        acc[1][nt] = (f32x4){0.f, 0.f, 0.f, 0.f};
    }
    __syncthreads();

#pragma unroll
    for (int ks = 0; ks < 4; ++ks) {
        short8 a0 = *(const short8*)(Xl + (mw * 32 + lid) * LD + ks * 32 + quad * 8);
        short8 a1 = *(const short8*)(Xl + (mw * 32 + 16 + lid) * LD + ks * 32 + quad * 8);
#pragma unroll
        for (int nt = 0; nt < 2; ++nt) {
            short8 bf = *(const short8*)(Wl + (nw * 32 + nt * 16 + lid) * LD + ks * 32 + quad * 8);
            acc[0][nt] = __builtin_amdgcn_mfma_f32_16x16x32_bf16(a0, bf, acc[0][nt], 0, 0, 0);
            acc[1][nt] = __builtin_amdgcn_mfma_f32_16x16x32_bf16(a1, bf, acc[1][nt], 0, 0, 0);
        }
    }

#pragma unroll
    for (int mt = 0; mt < 2; ++mt) {
#pragma unroll
        for (int nt = 0; nt < 2; ++nt) {
            int mbase = row0 + mw * 32 + mt * 16 + quad * 4;
            int n = nw * 32 + nt * 16 + lid;
            f32x4 v = acc[mt][nt];
#pragma unroll
            for (int r = 0; r < 4; ++r) {
                int row = mbase + r;
                if (row < N) {
                    unsigned int p = (unsigned int)__builtin_amdgcn_cvt_pk_fp8_f32(v[r], 0.f, 0, false);
                    z2[(size_t)row * 128 + n] = (unsigned char)(p & 0xFF);
                }
            }
        }
    }
}

// ---------------- k3: gather(Z2) + (1+deg)*c1 + b2a -> relu -> pooled sums -------------

__global__ __launch_bounds__(512, 6) void k3_kernel(const unsigned char* __restrict__ z2,
                                                    const int* __restrict__ deg,
                                                    const unsigned short* __restrict__ ell,
                                                    const float* __restrict__ c1,
                                                    const float* __restrict__ b2a,
                                                    const int* __restrict__ batch,
                                                    float* __restrict__ gsum) {
    constexpr int LD = 136;
    __shared__ short Xl[64 * LD];
    __shared__ short sorted[64];
    int tid = threadIdx.x;
    int lane = tid & 63, wave = tid >> 6;
    int row0 = blockIdx.x * 64;

    tile_sort(sorted, deg, row0, lane, wave);
    __syncthreads();

    {
        int grp = tid >> 3;
        int l   = tid & 7;
        int lr  = sorted[grp];
        const uint4* F16 = (const uint4*)z2;
        int n = row0 + lr;
        f32x2 a[8];
        if (n < N) {
            int dfull = deg[n];
            int dgc = min(dfull, D);
            set16(a, F16[(size_t)n * 8 + l]);       // self
            gather_rows(a, F16, ell + (size_t)n * D, dgc, l);
            float degf = (float)(1 + dfull);
            const f32x2* c1p = (const f32x2*)(c1 + l * 16);
            const f32x2* b2p = (const f32x2*)(b2a + l * 16);
#pragma unroll
            for (int q = 0; q < 8; ++q) {
                a[q] += degf * c1p[q] + b2p[q];
                a[q].x = fmaxf(a[q].x, 0.f);
                a[q].y = fmaxf(a[q].y, 0.f);
            }
        } else {
#pragma unroll
            for (int q = 0; q < 8; ++q) a[q] = (f32x2){0.f, 0.f};
        }
        uint4 o0, o1;
        o0.x = pack_bf16(a[0].x, a[0].y); o0.y = pack_bf16(a[1].x, a[1].y);
        o0.z = pack_bf16(a[2].x, a[2].y); o0.w = pack_bf16(a[3].x, a[3].y);
        o1.x = pack_bf16(a[4].x, a[4].y); o1.y = pack_bf16(a[5].x, a[5].y);
        o1.z = pack_bf16(a[6].x, a[6].y); o1.w = pack_bf16(a[7].x, a[7].y);
        uint4* xp = (uint4*)(Xl + lr * LD + l * 16);
        xp[0] = o0;
        xp[1] = o1;
    }
    __syncthreads();

    // pool: wave w owns rows [w*8, w*8+8) in NATURAL order; lane owns ch {2l, 2l+1}.
    int r0 = wave * 8;
    int gprev = -1;
    float a0 = 0.f, a1 = 0.f;
    for (int rr = 0; rr < 8; ++rr) {
        int row = row0 + r0 + rr;
        if (row >= N) break;
        int g = batch[row];
        if (g != gprev) {
            if (gprev >= 0) {
                atomicAdd(&gsum[gprev * C + 2 * lane], a0);
                atomicAdd(&gsum[gprev * C + 2 * lane + 1], a1);
            }
            gprev = g; a0 = 0.f; a1 = 0.f;
        }
        unsigned int pv = *(const unsigned int*)(Xl + (r0 + rr) * LD + 2 * lane);
        a0 += __uint_as_float((pv & 0xffffu) << 16);
        a1 += __uint_as_float(pv & 0xffff0000u);
    }
    if (gprev >= 0) {
        atomicAdd(&gsum[gprev * C + 2 * lane], a0);
        atomicAdd(&gsum[gprev * C + 2 * lane + 1], a1);
    }
}

// ---------------- head: out[g] = (gsum[g]/cnt) @ Whead + bhead  (all f32) --------------

__global__ __launch_bounds__(64) void head_kernel(const float* __restrict__ gsum,
                                                  const int* __restrict__ gcnt,
                                                  const float* __restrict__ Whead,
                                                  const float* __restrict__ bhead,
                                                  float* __restrict__ out) {
    int g = blockIdx.x;
    int t = threadIdx.x;   // 0..63
    __shared__ float pooled[C];
    float inv = 1.0f / (float)max(gcnt[g], 1);
    pooled[t]      = gsum[g * C + t] * inv;
    pooled[t + 64] = gsum[g * C + 64 + t] * inv;
    __syncthreads();
    float o = bhead[t];
#pragma unroll 4
    for (int k = 0; k < C; ++k) o += pooled[k] * Whead[k * OC + t];
    out[g * OC + t] = o;
}

// ---------------- launch ----------------

extern "C" void kernel_launch(void* const* d_in, const int* in_sizes, int n_in,
                              void* d_out, int out_size, void* d_ws, size_t ws_size,
                              hipStream_t stream) {
    const float* x    = (const float*)d_in[0];
    const int*   ei   = (const int*)d_in[1];   // [2,E]
    const int*   bat  = (const int*)d_in[2];
    const float* W1a  = (const float*)d_in[3];
    const float* b1a  = (const float*)d_in[4];
    const float* W1b  = (const float*)d_in[5];
    const float* b1b  = (const float*)d_in[6];
    const float* W2a  = (const float*)d_in[7];
    const float* b2a  = (const float*)d_in[8];
    const float* W2b  = (const float*)d_in[9];
    const float* b2b  = (const float*)d_in[10];
    const float* Wl   = (const float*)d_in[11];
    const float* bl   = (const float*)d_in[12];
    float*       out  = (float*)d_out;

    // workspace: [gsum G*C][gcnt G][bcount NBUCK]  <- one memset
    float* gsum    = (float*)d_ws;                         // G*C f32
    int*   gcnt    = (int*)(gsum + G * C);                 // G
    int*   bcount  = gcnt + G;                             // NBUCK
    int*   deg     = bcount + NBUCK;                       // N (written by fill)
    unsigned int*   bucketbuf = (unsigned int*)(deg + N);  // NBUCK*BCAP u32 (4 MB)
    unsigned short* ell  = (unsigned short*)(bucketbuf + (size_t)NBUCK * BCAP);  // N*D
    unsigned short* wtx  = ell + (size_t)N * D;            // 16384 bf16
    float* Whead = (float*)(wtx + 16384);                  // 128*64 f32
    float* c1    = Whead + 128 * OC;                       // 128 f32
    float* bhead = c1 + 128;                               // 64 f32
    unsigned char* z1 = (unsigned char*)(bhead + OC);      // N*128 fp8
    unsigned char* z2 = z1 + (size_t)N * 128;              // N*128 fp8

    const int* src = ei;
    const int* dst = ei + E;

    hipMemsetAsync(gsum, 0, (size_t)(G * C + G + NBUCK) * sizeof(int), stream);

    // prep: edge binning + gemma (Z1 = X@W1a) + weight fusions + gcnt histogram
    build_prep_kernel<<<EB + MB + WXB + WHB + 1 + GB, 512, 0, stream>>>(
        src, dst, bcount, bucketbuf, W1a, W1b, W2a, W2b, Wl, bl, b1b, b2b,
        wtx, Whead, c1, bhead, bat, gcnt, x, z1);

    // fill: per-bucket ELL fill (LDS cursors), writes deg
    fill_kernel<<<NBUCK, 512, 0, stream>>>(bcount, bucketbuf, ell, deg);

    // T1 = relu(Z1_i + sum Z1_j + b1a); Z2 = T1 @ (W1b@W2a) (fp8 table)
    k2_kernel<<<MB, 512, 0, stream>>>(z1, deg, ell, wtx, b1a, z2);
    // T2 = relu(Z2_i + sum Z2_j + (1+deg)*c1 + b2a); pool sums per graph
    k3_kernel<<<MB, 512, 0, stream>>>(z2, deg, ell, c1, b2a, bat, gsum);
    // out = (pooled mean) @ (W2b@Wl) + (b2b@Wl + bl)
    head_kernel<<<G, 64, 0, stream>>>(gsum, gcnt, Whead, bhead, out);
}

// Round 10
// 191.925 us; speedup vs baseline: 1.0874x; 1.0119x over previous
//
#include <hip/hip_runtime.h>

// Problem constants (from reference)
constexpr int N  = 50000;   // nodes
constexpr int E  = 800000;  // edges
constexpr int C  = 128;     // feature dim (IN_C == HID)
constexpr int G  = 256;     // graphs
constexpr int OC = 64;      // out channels
constexpr int D  = 64;      // ELL padded degree (Poisson(16): P(deg>=64) ~ 1e-20)

constexpr int NBUCK = 196;     // 256-node buckets: bucket = dst >> 8
constexpr int BCAP  = 5120;    // bucket capacity
constexpr int EPB = 2048;                      // edges per binning block
constexpr int EB  = (E + EPB - 1) / EPB;       // 391 edge-binning blocks
constexpr int WB1 = 64;                        // W1a^T -> bf16 blocks
constexpr int WXB = 64;                        // Wx = W1b@W2a -> bf16^T blocks
constexpr int WHB = 32;                        // Whead = W2b@Wl (f32) blocks
constexpr int GB  = (N + 255) / 256;           // 196 batch-histogram blocks
constexpr int FB  = NBUCK;                     // bucket-fill blocks in mid kernel
constexpr int MB  = (N + 63) / 64;             // 782 64-row tiles

typedef __attribute__((ext_vector_type(8))) short short8;
typedef __attribute__((ext_vector_type(4))) float f32x4;
typedef __attribute__((ext_vector_type(2))) float f32x2;

__device__ __forceinline__ unsigned int au(float f) { return __float_as_uint(f); }

__device__ __forceinline__ unsigned short f2bf(float f) {
    unsigned int u = au(f);
    u += 0x7fffu + ((u >> 16) & 1u);   // round-to-nearest-even
    return (unsigned short)(u >> 16);
}
__device__ __forceinline__ unsigned int pack_bf16(float lo, float hi) {
    return ((au(hi) + 0x8000u) & 0xFFFF0000u) | ((au(lo) + 0x8000u) >> 16);
}

// decode 16 fp8(e4m3) in uint4 -> accumulate into 8 float2
__device__ __forceinline__ void acc16(f32x2* a, uint4 v) {
    a[0] += __builtin_amdgcn_cvt_pk_f32_fp8((int)v.x, false);
    a[1] += __builtin_amdgcn_cvt_pk_f32_fp8((int)v.x, true);
    a[2] += __builtin_amdgcn_cvt_pk_f32_fp8((int)v.y, false);
    a[3] += __builtin_amdgcn_cvt_pk_f32_fp8((int)v.y, true);
    a[4] += __builtin_amdgcn_cvt_pk_f32_fp8((int)v.z, false);
    a[5] += __builtin_amdgcn_cvt_pk_f32_fp8((int)v.z, true);
    a[6] += __builtin_amdgcn_cvt_pk_f32_fp8((int)v.w, false);
    a[7] += __builtin_amdgcn_cvt_pk_f32_fp8((int)v.w, true);
}
__device__ __forceinline__ void set16(f32x2* a, uint4 v) {
    a[0] = __builtin_amdgcn_cvt_pk_f32_fp8((int)v.x, false);
    a[1] = __builtin_amdgcn_cvt_pk_f32_fp8((int)v.x, true);
    a[2] = __builtin_amdgcn_cvt_pk_f32_fp8((int)v.y, false);
    a[3] = __builtin_amdgcn_cvt_pk_f32_fp8((int)v.y, true);
    a[4] = __builtin_amdgcn_cvt_pk_f32_fp8((int)v.z, false);
    a[5] = __builtin_amdgcn_cvt_pk_f32_fp8((int)v.z, true);
    a[6] = __builtin_amdgcn_cvt_pk_f32_fp8((int)v.w, false);
    a[7] = __builtin_amdgcn_cvt_pk_f32_fp8((int)v.w, true);
}

// gather neighbor rows (fp8, 16 ch per lane), 4-deep pipeline with NEXT-index
// prefetch: the index pair for batch b+1 is issued before decoding batch b-1, so
// its ~200cy L2 latency hides under the decode instead of serializing ahead of
// the next 4 data loads.
__device__ __forceinline__ void gather_rows(f32x2* a, const uint4* F16,
                                            const unsigned short* irow, int dg, int l) {
    const uint2* i2 = (const uint2*)irow;   // 4 u16 indices per load
    int nb  = dg >> 2;
    int rem = dg & 3;
    if (nb > 0) {
        uint2 iu = i2[0];
        int t0 = (int)(iu.x & 0xffffu), t1 = (int)(iu.x >> 16);
        int t2 = (int)(iu.y & 0xffffu), t3 = (int)(iu.y >> 16);
        uint4 v0 = F16[(size_t)t0 * 8 + l];
        uint4 v1 = F16[(size_t)t1 * 8 + l];
        uint4 v2 = F16[(size_t)t2 * 8 + l];
        uint4 v3 = F16[(size_t)t3 * 8 + l];
        uint2 jn;
        if (nb > 1) jn = i2[1];
        for (int b = 1; b < nb; ++b) {
            int u0 = (int)(jn.x & 0xffffu), u1 = (int)(jn.x >> 16);
            int u2 = (int)(jn.y & 0xffffu), u3 = (int)(jn.y >> 16);
            uint4 w0 = F16[(size_t)u0 * 8 + l];
            uint4 w1 = F16[(size_t)u1 * 8 + l];
            uint4 w2 = F16[(size_t)u2 * 8 + l];
            uint4 w3 = F16[(size_t)u3 * 8 + l];
            if (b + 1 < nb) jn = i2[b + 1];   // prefetch next index pair
            // decode previous batch while w* (and jn) are in flight
            acc16(a, v0); acc16(a, v1); acc16(a, v2); acc16(a, v3);
            v0 = w0; v1 = w1; v2 = w2; v3 = w3;
        }
        acc16(a, v0); acc16(a, v1); acc16(a, v2); acc16(a, v3);
    }
    if (rem) {
        const unsigned short* ir = irow + nb * 4;
#pragma unroll
        for (int m = 0; m < 3; ++m) {
            if (m < rem) {
                uint4 v = F16[(size_t)ir[m] * 8 + l];
                acc16(a, v);
            }
        }
    }
}

// degree-rank sort of the 64 tile nodes (wave 0 only): sorted[rank] = local row.
// Waves then process near-equal-degree nodes -> minimal exec-mask divergence.
__device__ __forceinline__ void tile_sort(short* sorted, const int* deg, int row0,
                                          int lane, int wave) {
    if (wave == 0) {
        int n0 = row0 + lane;
        int key = (n0 < N) ? min(deg[n0], D) : -1;
        int rank = 0;
        for (int j = 0; j < 64; ++j) {
            int kj = __shfl(key, j);
            rank += (kj < key) || (kj == key && j < lane);
        }
        sorted[rank] = (short)lane;
    }
}

// ---------------- prep: edge binning || weight fusions || gcnt hist ----------------

__global__ __launch_bounds__(256) void build_prep_kernel(const int* __restrict__ src,
                                                         const int* __restrict__ dst,
                                                         int* __restrict__ bcount,
                                                         unsigned int* __restrict__ bucketbuf,
                                                         const float* __restrict__ W1a,
                                                         const float* __restrict__ W1b,
                                                         const float* __restrict__ W2a,
                                                         const float* __restrict__ W2b,
                                                         const float* __restrict__ Wl,
                                                         const float* __restrict__ bl,
                                                         const float* __restrict__ b1b,
                                                         const float* __restrict__ b2b,
                                                         unsigned short* __restrict__ wt1a,
                                                         unsigned short* __restrict__ wtx,
                                                         float* __restrict__ Whead,
                                                         float* __restrict__ c1,
                                                         float* __restrict__ bhead,
                                                         const int* __restrict__ batch,
                                                         int* __restrict__ gcnt) {
    int b = blockIdx.x;
    int tid = threadIdx.x;
    if (b < EB) {
        __shared__ int lcount[NBUCK];
        __shared__ int lbase[NBUCK];
        __shared__ int lcur[NBUCK];
        for (int i = tid; i < NBUCK; i += 256) { lcount[i] = 0; lcur[i] = 0; }
        __syncthreads();
        int e0 = b * EPB;
        int sv[8], dv[8];
#pragma unroll
        for (int i = 0; i < 8; ++i) {
            int e = e0 + i * 256 + tid;
            if (e < E) {
                sv[i] = src[e];
                dv[i] = dst[e];
                atomicAdd(&lcount[dv[i] >> 8], 1);
            } else {
                dv[i] = -1;
            }
        }
        __syncthreads();
        if (tid < NBUCK) {
            int c = lcount[tid];
            lbase[tid] = (c > 0) ? atomicAdd(&bcount[tid], c) : 0;
        }
        __syncthreads();
#pragma unroll
        for (int i = 0; i < 8; ++i) {
            if (dv[i] >= 0) {
                int bk = dv[i] >> 8;
                int pos = lbase[bk] + atomicAdd(&lcur[bk], 1);
                if (pos < BCAP)
                    bucketbuf[(size_t)bk * BCAP + pos] =
                        ((unsigned int)sv[i] << 16) | (unsigned int)(dv[i] & 255);
            }
        }
    } else if (b < EB + WB1) {
        // W1a^T -> bf16 [n][k]
        int idx = (b - EB) * 256 + tid;     // < 16384
        int n = idx >> 7, k = idx & 127;
        wt1a[idx] = f2bf(W1a[k * 128 + n]);
    } else if (b < EB + WB1 + WXB) {
        // Wx[i][j] = sum_k W1b[i][k]*W2a[k][j]; store transposed bf16 wtx[j][i]
        int idx = (b - EB - WB1) * 256 + tid;  // < 16384
        int i = idx >> 7, j = idx & 127;
        float acc = 0.f;
        for (int k = 0; k < 128; ++k) acc += W1b[i * 128 + k] * W2a[k * 128 + j];
        wtx[j * 128 + i] = f2bf(acc);
    } else if (b < EB + WB1 + WXB + WHB) {
        // Whead[i][j] = sum_k W2b[i][k]*Wl[k][j]  (f32, row-major [128][64])
        int idx = (b - EB - WB1 - WXB) * 256 + tid;  // < 8192
        int i = idx >> 6, j = idx & 63;
        float acc = 0.f;
        for (int k = 0; k < 128; ++k) acc += W2b[i * 128 + k] * Wl[k * OC + j];
        Whead[i * OC + j] = acc;
    } else if (b == EB + WB1 + WXB + WHB) {
        // bias fusions
        if (tid < 128) {
            float acc = 0.f;
            for (int k = 0; k < 128; ++k) acc += b1b[k] * W2a[k * 128 + tid];
            c1[tid] = acc;
        } else if (tid < 192) {
            int j = tid - 128;
            float acc = bl[j];
            for (int k = 0; k < 128; ++k) acc += b2b[k] * Wl[k * OC + j];
            bhead[j] = acc;
        }
    } else {
        // graph-size histogram (batch sorted)
        __shared__ int h[G];
        h[tid] = 0;
        __syncthreads();
        int i = (b - (EB + WB1 + WXB + WHB + 1)) * 256 + tid;
        if (i < N) atomicAdd(&h[batch[i]], 1);
        __syncthreads();
        int c = h[tid];
        if (c > 0) atomicAdd(&gcnt[tid], c);
    }
}

// ---------------- mid: bucket-fill (196 blocks) || GEMM Z1 = X@W1a (782 blocks) --------
// Both depend only on build_prep; merged into one 512-thread launch. Fill at 8 waves
// halves its serial iterations; its latency hides under the gemma blocks.

__global__ __launch_bounds__(512, 6) void mid_kernel(const int* __restrict__ bcount,
                                                     const unsigned int* __restrict__ bucketbuf,
                                                     unsigned short* __restrict__ ell,
                                                     int* __restrict__ deg,
                                                     const float* __restrict__ x,
                                                     const unsigned short* __restrict__ wt1a,
                                                     unsigned char* __restrict__ z1) {
    int tid = threadIdx.x;
    if (blockIdx.x < FB) {
        // ---- bucket fill: LDS cursors, node-major ELL [n][D], writes deg ----
        __shared__ int lcur[256];
        int b = blockIdx.x;
        if (tid < 256) lcur[tid] = 0;
        __syncthreads();
        int cnt = min(bcount[b], BCAP);
        const unsigned int* buf = bucketbuf + (size_t)b * BCAP;
        int nbase = b << 8;
        for (int i = tid; i < cnt; i += 512) {
            unsigned int e = buf[i];
            int dlow = (int)(e & 255u);
            int p = atomicAdd(&lcur[dlow], 1);
            if (p < D) ell[(size_t)(nbase + dlow) * D + p] = (unsigned short)(e >> 16);
        }
        __syncthreads();
        if (tid < 256) {
            int node = nbase + tid;
            if (node < N) deg[node] = lcur[tid];
        }
        return;
    }
    // ---- gemma: Z1 = X @ W1a (f32 in, fp8 out), 8-wave partition ----
    constexpr int LD = 136;
    __shared__ short Xl[64 * LD];
    __shared__ short Wl[128 * LD];
    int lane = tid & 63, wave = tid >> 6;
    int row0 = (blockIdx.x - FB) * 64;

    const short8* Wg = (const short8*)wt1a;
#pragma unroll
    for (int i = tid; i < 2048; i += 512) {
        int r = i >> 4, c = i & 15;
        *((short8*)(Wl + r * LD) + c) = Wg[i];
    }
    const float4* x4 = (const float4*)(x + (size_t)row0 * C);
#pragma unroll
    for (int i = tid; i < 2048; i += 512) {
        int r = i >> 5, c4 = i & 31;
        float4 v = (row0 + r < N) ? x4[i] : make_float4(0.f, 0.f, 0.f, 0.f);
        uint2 u;
        u.x = pack_bf16(v.x, v.y);
        u.y = pack_bf16(v.z, v.w);
        *(uint2*)(Xl + r * LD + c4 * 4) = u;
    }

    int mw = wave >> 2, nw = wave & 3;
    int lid = lane & 15, quad = lane >> 4;
    f32x4 acc[2][2];
#pragma unroll
    for (int nt = 0; nt < 2; ++nt) {
        acc[0][nt] = (f32x4){0.f, 0.f, 0.f, 0.f};
        acc[1][nt] = (f32x4){0.f, 0.f, 0.f, 0.f};
    }
    __syncthreads();

#pragma unroll
    for (int ks = 0; ks < 4; ++ks) {
        short8 a0 = *(const short8*)(Xl + (mw * 32 + lid) * LD + ks * 32 + quad * 8);
        short8 a1 = *(const short8*)(Xl + (mw * 32 + 16 + lid) * LD + ks * 32 + quad * 8);
#pragma unroll
        for (int nt = 0; nt < 2; ++nt) {
            short8 bf = *(const short8*)(Wl + (nw * 32 + nt * 16 + lid) * LD + ks * 32 + quad * 8);
            acc[0][nt] = __builtin_amdgcn_mfma_f32_16x16x32_bf16(a0, bf, acc[0][nt], 0, 0, 0);
            acc[1][nt] = __builtin_amdgcn_mfma_f32_16x16x32_bf16(a1, bf, acc[1][nt], 0, 0, 0);
        }
    }

#pragma unroll
    for (int mt = 0; mt < 2; ++mt) {
#pragma unroll
        for (int nt = 0; nt < 2; ++nt) {
            int mbase = row0 + mw * 32 + mt * 16 + quad * 4;
            int n = nw * 32 + nt * 16 + lid;
            f32x4 v = acc[mt][nt];
#pragma unroll
            for (int r = 0; r < 4; ++r) {
                int row = mbase + r;
                if (row < N) {
                    unsigned int p = (unsigned int)__builtin_amdgcn_cvt_pk_fp8_f32(v[r], 0.f, 0, false);
                    z1[(size_t)row * 128 + n] = (unsigned char)(p & 0xFF);
                }
            }
        }
    }
}

// ---------------- k2: gather(Z1) + b1a -> relu -> GEMM(Wx) -> Z2 fp8 table -------------

__global__ __launch_bounds__(512, 6) void k2_kernel(const unsigned char* __restrict__ z1,
                                                    const int* __restrict__ deg,
                                                    const unsigned short* __restrict__ ell,
                                                    const unsigned short* __restrict__ wtx,
                                                    const float* __restrict__ b1a,
                                                    unsigned char* __restrict__ z2) {
    constexpr int LD = 136;
    __shared__ short Xl[64 * LD];
    __shared__ short Wl[128 * LD];
    __shared__ short sorted[64];
    int tid = threadIdx.x;
    int lane = tid & 63, wave = tid >> 6;
    int row0 = blockIdx.x * 64;

    const short8* Wg = (const short8*)wtx;
#pragma unroll
    for (int i = tid; i < 2048; i += 512) {
        int r = i >> 4, c = i & 15;
        *((short8*)(Wl + r * LD) + c) = Wg[i];
    }
    tile_sort(sorted, deg, row0, lane, wave);
    __syncthreads();

    {
        int grp = tid >> 3;   // 0..63: rank in degree order
        int l   = tid & 7;    // 16 channels each
        int lr  = sorted[grp];
        const uint4* F16 = (const uint4*)z1;
        int n = row0 + lr;
        f32x2 a[8];
        if (n < N) {
            int dgc = min(deg[n], D);
            set16(a, F16[(size_t)n * 8 + l]);       // self
            gather_rows(a, F16, ell + (size_t)n * D, dgc, l);
            const f32x2* bp = (const f32x2*)(b1a + l * 16);
#pragma unroll
            for (int q = 0; q < 8; ++q) {
                a[q] += bp[q];
                a[q].x = fmaxf(a[q].x, 0.f);
                a[q].y = fmaxf(a[q].y, 0.f);
            }
        } else {
#pragma unroll
            for (int q = 0; q < 8; ++q) a[q] = (f32x2){0.f, 0.f};
        }
        uint4 o0, o1;
        o0.x = pack_bf16(a[0].x, a[0].y); o0.y = pack_bf16(a[1].x, a[1].y);
        o0.z = pack_bf16(a[2].x, a[2].y); o0.w = pack_bf16(a[3].x, a[3].y);
        o1.x = pack_bf16(a[4].x, a[4].y); o1.y = pack_bf16(a[5].x, a[5].y);
        o1.z = pack_bf16(a[6].x, a[6].y); o1.w = pack_bf16(a[7].x, a[7].y);
        uint4* xp = (uint4*)(Xl + lr * LD + l * 16);
        xp[0] = o0;
        xp[1] = o1;
    }

    int mw = wave >> 2, nw = wave & 3;
    int lid = lane & 15, quad = lane >> 4;
    f32x4 acc[2][2];
#pragma unroll
    for (int nt = 0; nt < 2; ++nt) {
        acc[0][nt] = (f32x4){0.f, 0.f, 0.f, 0.f};
        acc[1][nt] = (f32x4){0.f, 0.f, 0.f, 0.f};
    }
    __syncthreads();

#pragma unroll
    for (int ks = 0; ks < 4; ++ks) {
        short8 a0 = *(const short8*)(Xl + (mw * 32 + lid) * LD + ks * 32 + quad * 8);
        short8 a1 = *(const short8*)(Xl + (mw * 32 + 16 + lid) * LD + ks * 32 + quad * 8);
#pragma unroll
        for (int nt = 0; nt < 2; ++nt) {
            short8 bf = *(const short8*)(Wl + (nw * 32 + nt * 16 + lid) * LD + ks * 32 + quad * 8);
            acc[0][nt] = __builtin_amdgcn_mfma_f32_16x16x32_bf16(a0, bf, acc[0][nt], 0, 0, 0);
            acc[1][nt] = __builtin_amdgcn_mfma_f32_16x16x32_bf16(a1, bf, acc[1][nt], 0, 0, 0);
        }
    }

#pragma unroll
    for (int mt = 0; mt < 2; ++mt) {
#pragma unroll
        for (int nt = 0; nt < 2; ++nt) {
            int mbase = row0 + mw * 32 + mt * 16 + quad * 4;
            int n = nw * 32 + nt * 16 + lid;
            f32x4 v = acc[mt][nt];
#pragma unroll
            for (int r = 0; r < 4; ++r) {
                int row = mbase + r;
                if (row < N) {
                    unsigned int p = (unsigned int)__builtin_amdgcn_cvt_pk_fp8_f32(v[r], 0.f, 0, false);
                    z2[(size_t)row * 128 + n] = (unsigned char)(p & 0xFF);
                }
            }
        }
    }
}

// ---------------- k3: gather(Z2) + (1+deg)*c1 + b2a -> relu -> pooled sums -------------

__global__ __launch_bounds__(512, 6) void k3_kernel(const unsigned char* __restrict__ z2,
                                                    const int* __restrict__ deg,
                                                    const unsigned short* __restrict__ ell,
                                                    const float* __restrict__ c1,
                                                    const float* __restrict__ b2a,
                                                    const int* __restrict__ batch,
                                                    float* __restrict__ gsum) {
    constexpr int LD = 136;
    __shared__ short Xl[64 * LD];
    __shared__ short sorted[64];
    int tid = threadIdx.x;
    int lane = tid & 63, wave = tid >> 6;
    int row0 = blockIdx.x * 64;

    tile_sort(sorted, deg, row0, lane, wave);
    __syncthreads();

    {
        int grp = tid >> 3;
        int l   = tid & 7;
        int lr  = sorted[grp];
        const uint4* F16 = (const uint4*)z2;
        int n = row0 + lr;
        f32x2 a[8];
        if (n < N) {
            int dfull = deg[n];
            int dgc = min(dfull, D);
            set16(a, F16[(size_t)n * 8 + l]);       // self
            gather_rows(a, F16, ell + (size_t)n * D, dgc, l);
            float degf = (float)(1 + dfull);
            const f32x2* c1p = (const f32x2*)(c1 + l * 16);
            const f32x2* b2p = (const f32x2*)(b2a + l * 16);
#pragma unroll
            for (int q = 0; q < 8; ++q) {
                a[q] += degf * c1p[q] + b2p[q];
                a[q].x = fmaxf(a[q].x, 0.f);
                a[q].y = fmaxf(a[q].y, 0.f);
            }
        } else {
#pragma unroll
            for (int q = 0; q < 8; ++q) a[q] = (f32x2){0.f, 0.f};
        }
        uint4 o0, o1;
        o0.x = pack_bf16(a[0].x, a[0].y); o0.y = pack_bf16(a[1].x, a[1].y);
        o0.z = pack_bf16(a[2].x, a[2].y); o0.w = pack_bf16(a[3].x, a[3].y);
        o1.x = pack_bf16(a[4].x, a[4].y); o1.y = pack_bf16(a[5].x, a[5].y);
        o1.z = pack_bf16(a[6].x, a[6].y); o1.w = pack_bf16(a[7].x, a[7].y);
        uint4* xp = (uint4*)(Xl + lr * LD + l * 16);
        xp[0] = o0;
        xp[1] = o1;
    }
    __syncthreads();

    // pool: wave w owns rows [w*8, w*8+8) in NATURAL order (Xl rows are at original
    // slots regardless of which group computed them); lane owns channels {2l, 2l+1}.
    int r0 = wave * 8;
    int gprev = -1;
    float a0 = 0.f, a1 = 0.f;
    for (int rr = 0; rr < 8; ++rr) {
        int row = row0 + r0 + rr;
        if (row >= N) break;
        int g = batch[row];
        if (g != gprev) {
            if (gprev >= 0) {
                atomicAdd(&gsum[gprev * C + 2 * lane], a0);
                atomicAdd(&gsum[gprev * C + 2 * lane + 1], a1);
            }
            gprev = g; a0 = 0.f; a1 = 0.f;
        }
        unsigned int pv = *(const unsigned int*)(Xl + (r0 + rr) * LD + 2 * lane);
        a0 += __uint_as_float((pv & 0xffffu) << 16);
        a1 += __uint_as_float(pv & 0xffff0000u);
    }
    if (gprev >= 0) {
        atomicAdd(&gsum[gprev * C + 2 * lane], a0);
        atomicAdd(&gsum[gprev * C + 2 * lane + 1], a1);
    }
}

// ---------------- head: out[g] = (gsum[g]/cnt) @ Whead + bhead  (all f32) --------------

__global__ __launch_bounds__(64) void head_kernel(const float* __restrict__ gsum,
                                                  const int* __restrict__ gcnt,
                                                  const float* __restrict__ Whead,
                                                  const float* __restrict__ bhead,
                                                  float* __restrict__ out) {
    int g = blockIdx.x;
    int t = threadIdx.x;   // 0..63
    __shared__ float pooled[C];
    float inv = 1.0f / (float)max(gcnt[g], 1);
    pooled[t]      = gsum[g * C + t] * inv;
    pooled[t + 64] = gsum[g * C + 64 + t] * inv;
    __syncthreads();
    float o = bhead[t];
#pragma unroll 4
    for (int k = 0; k < C; ++k) o += pooled[k] * Whead[k * OC + t];
    out[g * OC + t] = o;
}

// ---------------- launch ----------------

extern "C" void kernel_launch(void* const* d_in, const int* in_sizes, int n_in,
                              void* d_out, int out_size, void* d_ws, size_t ws_size,
                              hipStream_t stream) {
    const float* x    = (const float*)d_in[0];
    const int*   ei   = (const int*)d_in[1];   // [2,E]
    const int*   bat  = (const int*)d_in[2];
    const float* W1a  = (const float*)d_in[3];
    const float* b1a  = (const float*)d_in[4];
    const float* W1b  = (const float*)d_in[5];
    const float* b1b  = (const float*)d_in[6];
    const float* W2a  = (const float*)d_in[7];
    const float* b2a  = (const float*)d_in[8];
    const float* W2b  = (const float*)d_in[9];
    const float* b2b  = (const float*)d_in[10];
    const float* Wl   = (const float*)d_in[11];
    const float* bl   = (const float*)d_in[12];
    float*       out  = (float*)d_out;

    // workspace: [gsum G*C][gcnt G][bcount NBUCK]  <- one memset
    float* gsum    = (float*)d_ws;                         // G*C f32
    int*   gcnt    = (int*)(gsum + G * C);                 // G
    int*   bcount  = gcnt + G;                             // NBUCK
    int*   deg     = bcount + NBUCK;                       // N (written by mid fill)
    unsigned int*   bucketbuf = (unsigned int*)(deg + N);  // NBUCK*BCAP u32 (4 MB)
    unsigned short* ell  = (unsigned short*)(bucketbuf + (size_t)NBUCK * BCAP);  // N*D
    unsigned short* wt1a = ell + (size_t)N * D;            // 16384 bf16
    unsigned short* wtx  = wt1a + 16384;                   // 16384 bf16
    float* Whead = (float*)(wtx + 16384);                  // 128*64 f32
    float* c1    = Whead + 128 * OC;                       // 128 f32
    float* bhead = c1 + 128;                               // 64 f32
    unsigned char* z1 = (unsigned char*)(bhead + OC);      // N*128 fp8
    unsigned char* z2 = z1 + (size_t)N * 128;              // N*128 fp8

    const int* src = ei;
    const int* dst = ei + E;

    hipMemsetAsync(gsum, 0, (size_t)(G * C + G + NBUCK) * sizeof(int), stream);

    // prep: edge binning + weight fusions + gcnt histogram
    build_prep_kernel<<<EB + WB1 + WXB + WHB + 1 + GB, 256, 0, stream>>>(
        src, dst, bcount, bucketbuf, W1a, W1b, W2a, W2b, Wl, bl, b1b, b2b,
        wt1a, wtx, Whead, c1, bhead, bat, gcnt);

    // mid: bucket fill (196 blocks) || Z1 = X @ W1a (782 blocks)
    mid_kernel<<<FB + MB, 512, 0, stream>>>(bcount, bucketbuf, ell, deg,
                                            x, wt1a, z1);

    // T1 = relu(Z1_i + sum Z1_j + b1a); Z2 = T1 @ (W1b@W2a) (fp8 table)
    k2_kernel<<<MB, 512, 0, stream>>>(z1, deg, ell, wtx, b1a, z2);
    // T2 = relu(Z2_i + sum Z2_j + (1+deg)*c1 + b2a); pool sums per graph
    k3_kernel<<<MB, 512, 0, stream>>>(z2, deg, ell, c1, b2a, bat, gsum);
    // out = (pooled mean) @ (W2b@Wl) + (b2b@Wl + bl)
    head_kernel<<<G, 64, 0, stream>>>(gsum, gcnt, Whead, bhead, out);
}